// Round 14
// baseline (115.002 us; speedup 1.0000x reference)
//
#include <hip/hip_runtime.h>
#include <math.h>

// Problem constants
#define BATCH  8
#define NVERT  8192
#define NCELL  4096            // 64*64 grid cells per batch
#define TPB    16              // tile-blocks per batch (4x4 tiles of 16x16)
#define WPB    16              // waves per block
#define KR     32              // vertices per MFMA round
#define KCHW   (NVERT / WPB)   // 512 vertices per wave
#define ROUNDS (KCHW / KR)     // 16
#define POISON 0xAAAAAAAAu

#ifndef M_PI
#define M_PI 3.14159265358979323846
#endif

typedef __attribute__((ext_vector_type(8))) short  bf16x8;
typedef __attribute__((ext_vector_type(4))) float  f32x4;

static __device__ __forceinline__ float fast_exp2(float x) {
#if __has_builtin(__builtin_amdgcn_exp2f)
    return __builtin_amdgcn_exp2f(x);
#else
    return exp2f(x);
#endif
}

// RNE float->bf16 pair pack: low 16 = a, high 16 = b.
static __device__ __forceinline__ unsigned int pack_bf16(float a, float b) {
    unsigned int ua = __float_as_uint(a), ub = __float_as_uint(b);
    ua += 0x7fffu + ((ua >> 16) & 1u);
    ub += 0x7fffu + ((ub >> 16) & 1u);
    return (ua >> 16) | (ub & 0xffff0000u);
}

// ---------------------------------------------------------------------------
// Single worker dispatch, NO polling. Grid = 128 blocks x 1024 threads
// (16 waves => 4 waves/SIMD at 1 block/CU: latency chain overlapped 4x —
// the fix for R13's 1-wave/SIMD serialization).
// Block (b, t): one 16x16 cell tile over the FULL K=8192. Wave w owns
// K-chunk [w*512, (w+1)*512): per 32-vertex round it stages wave-private
// ex[16 rows][32 k] / ey[16 cols][32 k] bf16 panels in LDS (same-wave
// produce->consume, compiler-ordered lgkmcnt, zero barriers) and issues
// 1x mfma_f32_16x16x32_bf16. Cross-wave K-sum (16 waves) in LDS, raw tile
// written to out. Election: fence + one atomicAdd(cnt[b]); the 16th block
// (old==15; cnt zeroed by a 32-byte memset node) re-reads the batch's 4096
// raw values, total = their exact sum (bf16 bias cancels in the ratio),
// normalizes in place. Deterministic everywhere.
// ---------------------------------------------------------------------------
__global__ __launch_bounds__(1024) void kde_last(const float* __restrict__ T,
                                                 unsigned int* __restrict__ cnt,
                                                 float* __restrict__ out) {
    const int blk = blockIdx.x;
    const int b   = blk >> 4;
    const int t   = blk & 15;
    const int tr0 = (t >> 2) << 4;             // tile x-row base
    const int tc0 = (t & 3) << 4;              // tile y-col base
    const int tid = threadIdx.x;
    const int w    = tid >> 6;                 // wave id 0..15
    const int lane = tid & 63;

    __shared__ __align__(16) unsigned short es[WPB][2][16][40]; // 40960 B
    __shared__ float red[WPB][4];
    __shared__ float gsum[WPB][16][17];        // cross-wave K-sum (pad 17)
    __shared__ float bc[3];                    // kexp2, scale, factor
    __shared__ unsigned int lastflag;

    // ---- phase 0: sigma over the full batch (redundant per block) ----
    const float4* T4 = reinterpret_cast<const float4*>(T + (size_t)b * NVERT * 2);
    float sx = 0.f, sx2 = 0.f, sy = 0.f, sy2 = 0.f;
    for (int q = tid; q < NVERT / 2; q += 1024) {  // 2 vertices per float4
        float4 v = T4[q];
        sx += v.x + v.z;
        sy += v.y + v.w;
        sx2 += v.x * v.x + v.z * v.z;
        sy2 += v.y * v.y + v.w * v.w;
    }
    for (int off = 32; off; off >>= 1) {
        sx  += __shfl_down(sx,  off);  sx2 += __shfl_down(sx2, off);
        sy  += __shfl_down(sy,  off);  sy2 += __shfl_down(sy2, off);
    }
    if (lane == 0) { red[w][0] = sx; red[w][1] = sx2; red[w][2] = sy; red[w][3] = sy2; }
    __syncthreads();
    if (tid == 0) {
        double tsx = 0, tsx2 = 0, tsy = 0, tsy2 = 0;
        for (int i = 0; i < WPB; ++i) {
            tsx += red[i][0]; tsx2 += red[i][1]; tsy += red[i][2]; tsy2 += red[i][3];
        }
        const double N = (double)NVERT;
        double varx = (tsx2 - tsx * tsx / N) / (N - 1.0);
        double vary = (tsy2 - tsy * tsy / N) / (N - 1.0);
        double sigma = 0.5 * (sqrt(varx) + sqrt(vary));
        const double BD = 1.0 / 63.0;
        if (sigma < BD) sigma = BD;
        const double C2 = pow(2.0, -13.0 / 3.0);   // C^2, C = NV^(-1/6)
        double s2 = sigma * sigma;
        bc[0] = (float)(-0.5 / C2 / (s2 * 0.69314718055994530942)); // exp2 coeff
        bc[1] = (float)(1.0 / (2.0 * M_PI * C2) / (s2 * N));        // CF*s^-2/NV
    }
    __syncthreads();
    const float kexp2 = bc[0];

    // ---- staging constants (hoisted) ----
    // Lanes 0-31: ex plane (tile rows); lanes 32-63: ey plane (tile cols).
    // vp = vertex-pair 0..15; rb = row base 0/8; lane stages rows rb..rb+7.
    const int   vp    = lane & 15;
    const int   plane = lane >> 5;
    const int   rb    = ((lane >> 4) & 1) * 8;
    const int   base0 = plane ? tc0 : tr0;
    float c1[8], m2[8];
#pragma unroll
    for (int i = 0; i < 8; ++i) {
        float xg = (float)(base0 + rb + i) * (1.0f / 63.0f);
        m2[i] = -2.0f * kexp2 * xg;            // arg = m2*t + (kexp2*xg^2 + kexp2*t^2)
        c1[i] = kexp2 * xg * xg;
    }

    // ---- phase 1: full-K MFMA loop, wave-private staging, ZERO barriers ----
    unsigned short (*exw)[40] = es[w][0];
    unsigned short (*eyw)[40] = es[w][1];
    unsigned short (*dstT)[40] = es[w][plane];
    const float4* T4v = reinterpret_cast<const float4*>(T) + (size_t)b * 4096 + w * 256;

    const int frow = lane & 15;                // fragment row/col
    const int kq   = lane >> 4;                // k-quarter 0..3
    f32x4 acc = (f32x4){0.f, 0.f, 0.f, 0.f};

    for (int r = 0; r < ROUNDS; ++r) {
        float4 tt = T4v[r * 16 + vp];          // verts (2j, 2j+1)
        float t0 = plane ? tt.y : tt.x;
        float t1 = plane ? tt.w : tt.z;
        float kt20 = kexp2 * t0 * t0;
        float kt21 = kexp2 * t1 * t1;
#pragma unroll
        for (int i = 0; i < 8; ++i) {
            float e0 = fast_exp2(fmaf(m2[i], t0, c1[i] + kt20));
            float e1 = fast_exp2(fmaf(m2[i], t1, c1[i] + kt21));
            *reinterpret_cast<unsigned int*>(&dstT[rb + i][vp * 2]) = pack_bf16(e0, e1);
        }
        // same-wave DS ordering: compiler inserts lgkmcnt between the writes
        // above and the dependent reads below (aliasing through es).
        bf16x8 af = *reinterpret_cast<const bf16x8*>(&exw[frow][kq << 3]);
        bf16x8 bf = *reinterpret_cast<const bf16x8*>(&eyw[frow][kq << 3]);
        acc = __builtin_amdgcn_mfma_f32_16x16x32_bf16(af, bf, acc, 0, 0, 0);
    }

    // ---- phase 2: cross-wave K-sum (16 waves), write raw tile ----
    // D layout (m89-verified): col = lane&15, row = (lane>>4)*4 + reg.
#pragma unroll
    for (int ri = 0; ri < 4; ++ri)
        gsum[w][(kq << 2) + ri][frow] = acc[ri];
    __syncthreads();
    if (tid < 256) {
        const int rr = tid >> 4, cc = tid & 15;
        float s0 = 0.f, s1 = 0.f;
#pragma unroll
        for (int wv = 0; wv < WPB; wv += 2) {
            s0 += gsum[wv][rr][cc];
            s1 += gsum[wv + 1][rr][cc];
        }
        out[b * NCELL + (tr0 + rr) * 64 + tc0 + cc] = s0 + s1;
    }

    // ---- release + last-block election (single atomic, NO polling) ----
    __threadfence();
    __syncthreads();
    if (tid == 0) {
        unsigned int old = atomicAdd(&cnt[b], 1u);
        lastflag = (old == 15u || old == POISON + 15u) ? 1u : 0u;
    }
    __syncthreads();
    if (!lastflag) return;

    // ---- phase 3 (last block of batch only): total + normalize in place ----
    __threadfence();                           // acquire: see all 16 tiles
    float* ob = out + b * NCELL;
    float v[4];
    float s = 0.f;
#pragma unroll
    for (int i = 0; i < 4; ++i) {              // coalesced, deterministic order
        v[i] = ob[i * 1024 + tid];
        s += v[i];
    }
    for (int off = 32; off; off >>= 1) s += __shfl_down(s, off);
    if (lane == 0) red[w][0] = s;
    __syncthreads();
    if (tid == 0) {
        float tot = 0.f;
        for (int i = 0; i < WPB; ++i) tot += red[i][0];
        const float scale = bc[1];
        const float denom = fmaxf(tot * scale, 1e-5f);
        bc[2] = scale / denom;
    }
    __syncthreads();
    const float factor = bc[2];
#pragma unroll
    for (int i = 0; i < 4; ++i)
        ob[i * 1024 + tid] = v[i] * factor;
}

// ---------------------------------------------------------------------------
extern "C" void kernel_launch(void* const* d_in, const int* in_sizes, int n_in,
                              void* d_out, int out_size, void* d_ws, size_t ws_size,
                              hipStream_t stream) {
    const float* T = (const float*)d_in[0];   // [B, NV, 2] f32
    // d_in[1] (S) is a deterministic 64x64 meshgrid in [0,1]^2 — derived inline.

    unsigned int* cnt = (unsigned int*)d_ws;  // 8 counters
    hipMemsetAsync(cnt, 0, BATCH * sizeof(unsigned int), stream);
    kde_last<<<BATCH * TPB, 1024, 0, stream>>>(T, cnt, (float*)d_out);
}

// Round 15
// 105.907 us; speedup vs baseline: 1.0859x; 1.0859x over previous
//
#include <hip/hip_runtime.h>
#include <math.h>

// Problem constants
#define BATCH  8
#define NVERT  8192
#define NCELL  4096            // 64*64 grid cells per batch
#define SPLITS 32              // blocks per batch (split-K)
#define JPB    (NVERT / SPLITS) // 256 vertices per block
#define KR     32              // vertices per MFMA round
#define ROUNDS (JPB / KR)      // 8
#define POISON 0xAAAAAAAAu

#ifndef M_PI
#define M_PI 3.14159265358979323846
#endif

// ws layout (floats)
#define PARTIALS_OFF 1024      // float partials[256*4096] = 4 MB (cnt in [0..7])

typedef __attribute__((ext_vector_type(8))) short  bf16x8;
typedef __attribute__((ext_vector_type(4))) float  f32x4;

static __device__ __forceinline__ float fast_exp2(float x) {
#if __has_builtin(__builtin_amdgcn_exp2f)
    return __builtin_amdgcn_exp2f(x);
#else
    return exp2f(x);
#endif
}

// RNE float->bf16 pair pack: low 16 = a, high 16 = b.
static __device__ __forceinline__ unsigned int pack_bf16(float a, float b) {
    unsigned int ua = __float_as_uint(a), ub = __float_as_uint(b);
    ua += 0x7fffu + ((ua >> 16) & 1u);
    ub += 0x7fffu + ((ub >> 16) & 1u);
    return (ua >> 16) | (ub & 0xffff0000u);
}

// ---------------------------------------------------------------------------
// One worker dispatch (plus a 32 B memset node), NO polling.
// Grid = BATCH*SPLITS = 256 blocks x 256 threads (4 waves, 1 block/CU).
// Each block: sigma (redundant per block) + R10's split-K MFMA kde on its
// 256-vertex slice (8 double-buffered rounds, 1 barrier/round) -> one
// 16 KB partial slice. Then fence + atomicAdd(cnt[b]); the unique LAST
// block of the batch (old==31) re-reads the 32 slices, computes cell sums
// AND the batch total from the same values (denominator bias cancels),
// normalizes, writes out. Single atomic per block, no loops on memory.
// ---------------------------------------------------------------------------
__global__ __launch_bounds__(256) void kde_elect(const float* __restrict__ T,
                                                 unsigned int* __restrict__ cnt,
                                                 float* __restrict__ partials,
                                                 float* __restrict__ out) {
    const int blk = blockIdx.x;
    const int b   = blk >> 5;                  // / SPLITS
    const int sp  = blk & (SPLITS - 1);
    const int j0  = sp * JPB;
    const int tid = threadIdx.x;
    const int w    = tid >> 6;                 // wave id 0..3
    const int lane = tid & 63;

    __shared__ __align__(16) unsigned short exT[2][64][40];  // 10240 B
    __shared__ __align__(16) unsigned short eyT[2][64][40];  // 10240 B
    __shared__ float2 tj[JPB];                 // this block's vertex slice (2 KB)
    __shared__ float  red[4][4];
    __shared__ float  bc[3];                   // kexp2, scale, factor
    __shared__ unsigned int lastflag;

    // ---- phase 0: sigma over the full batch (redundant per block) ----
    const float4* T4 = reinterpret_cast<const float4*>(T + (size_t)b * NVERT * 2);
    float sx = 0.f, sx2 = 0.f, sy = 0.f, sy2 = 0.f;
    for (int q = tid; q < NVERT / 2; q += 256) {   // 2 vertices per float4
        float4 v = T4[q];
        sx += v.x + v.z;
        sy += v.y + v.w;
        sx2 += v.x * v.x + v.z * v.z;
        sy2 += v.y * v.y + v.w * v.w;
        int local = 2 * q - j0;                    // even when in range
        if ((unsigned)local < (unsigned)JPB)
            *reinterpret_cast<float4*>(&tj[local]) = v;
    }
    for (int off = 32; off; off >>= 1) {
        sx  += __shfl_down(sx,  off);  sx2 += __shfl_down(sx2, off);
        sy  += __shfl_down(sy,  off);  sy2 += __shfl_down(sy2, off);
    }
    if (lane == 0) { red[w][0] = sx; red[w][1] = sx2; red[w][2] = sy; red[w][3] = sy2; }
    __syncthreads();
    if (tid == 0) {
        double tsx = 0, tsx2 = 0, tsy = 0, tsy2 = 0;
        for (int i = 0; i < 4; ++i) {
            tsx += red[i][0]; tsx2 += red[i][1]; tsy += red[i][2]; tsy2 += red[i][3];
        }
        const double N = (double)NVERT;
        double varx = (tsx2 - tsx * tsx / N) / (N - 1.0);
        double vary = (tsy2 - tsy * tsy / N) / (N - 1.0);
        double sigma = 0.5 * (sqrt(varx) + sqrt(vary));
        const double BD = 1.0 / 63.0;
        if (sigma < BD) sigma = BD;
        const double C2 = pow(2.0, -13.0 / 3.0);   // C^2, C = NV^(-1/6)
        double s2 = sigma * sigma;
        bc[0] = (float)(-0.5 / C2 / (s2 * 0.69314718055994530942)); // exp2 coeff
        bc[1] = (float)(1.0 / (2.0 * M_PI * C2) / (s2 * N));        // CF*s^-2/NV
    }
    __syncthreads();
    const float kexp2 = bc[0];

    // ---- staging constants (R10-proven layout) ----
    // Wave w stages plane (w&1: 0=x,1=y), vertex half jh=(w>>1)*16 of each
    // 32-vertex round; lane = gx (0..63). 8 vertex-pairs -> 8 ds_write_b32.
    const float xg   = (float)lane * (1.0f / 63.0f);
    const int   jh   = (w >> 1) << 4;          // 0 or 16
    const bool  isY  = (w & 1);

#define STAGE(R, BUF)                                                       \
    {                                                                       \
        unsigned short (*dstT)[40] = isY ? eyT[BUF] : exT[BUF];             \
        _Pragma("unroll")                                                   \
        for (int jp = 0; jp < 8; ++jp) {                                    \
            int jl = jh + jp * 2;                                           \
            float4 tt = *reinterpret_cast<const float4*>(&tj[(R) * KR + jl]);\
            float tv0 = isY ? tt.y : tt.x;                                  \
            float tv1 = isY ? tt.w : tt.z;                                  \
            float d0 = xg - tv0, d1 = xg - tv1;                             \
            float e0 = fast_exp2(kexp2 * d0 * d0);                          \
            float e1 = fast_exp2(kexp2 * d1 * d1);                          \
            *reinterpret_cast<unsigned int*>(&dstT[lane][jl]) =             \
                pack_bf16(e0, e1);                                          \
        }                                                                   \
    }

    // ---- phase 1: MFMA main loop, double-buffered, 1 barrier per round ----
    const int col16 = lane & 15;
    const int kq    = lane >> 4;               // k-quarter 0..3
    f32x4 acc[4];
#pragma unroll
    for (int ni = 0; ni < 4; ++ni) acc[ni] = (f32x4){0.f, 0.f, 0.f, 0.f};

    STAGE(0, 0);                               // prologue: round 0 -> buf 0
    for (int r = 0; r < ROUNDS; ++r) {
        __syncthreads();                       // round r staged; buf r+1 free
        if (r + 1 < ROUNDS) STAGE(r + 1, (r + 1) & 1);
        const int buf = r & 1;
        bf16x8 af = *reinterpret_cast<const bf16x8*>(&exT[buf][(w << 4) + col16][kq << 3]);
#pragma unroll
        for (int ni = 0; ni < 4; ++ni) {
            bf16x8 bfr = *reinterpret_cast<const bf16x8*>(&eyT[buf][(ni << 4) + col16][kq << 3]);
            acc[ni] = __builtin_amdgcn_mfma_f32_16x16x32_bf16(af, bfr, acc[ni], 0, 0, 0);
        }
    }

    // ---- phase 2: write this block's partial slice ----
    // D layout (m89-verified): col = lane&15, row = (lane>>4)*4 + reg.
    float* dst = partials + (size_t)blk * NCELL;
    const int rowbase = (w << 4) + (kq << 2);  // gx of reg r = rowbase + r
#pragma unroll
    for (int ni = 0; ni < 4; ++ni)
#pragma unroll
        for (int r = 0; r < 4; ++r)
            dst[(rowbase + r) * 64 + (ni << 4) + col16] = acc[ni][r];

    // ---- release + last-block election (single atomic, NO polling) ----
    __threadfence();
    __syncthreads();
    if (tid == 0) {
        unsigned int old = atomicAdd(&cnt[b], 1u);
        lastflag = (old == (SPLITS - 1) || old == POISON + (SPLITS - 1)) ? 1u : 0u;
    }
    __syncthreads();
    if (!lastflag) return;

    // ---- phase 3 (last block of batch): sum 32 slices, total, normalize ----
    __threadfence();                           // acquire: see all slices
    const float4* pb = reinterpret_cast<const float4*>(partials + (size_t)(b << 5) * NCELL);
    float4 csum[4];
    float tsum = 0.f;
#pragma unroll
    for (int q = 0; q < 4; ++q) {              // 4 float4-columns per thread
        const float4* col = pb + q * 256 + tid;
        float4 s0 = col[0 * 1024], s1 = col[1 * 1024];
        float4 s2 = col[2 * 1024], s3 = col[3 * 1024];
#pragma unroll
        for (int s = 4; s < SPLITS; s += 4) {  // 4 independent chains
            float4 a0 = col[(s + 0) * 1024], a1 = col[(s + 1) * 1024];
            float4 a2 = col[(s + 2) * 1024], a3 = col[(s + 3) * 1024];
            s0.x += a0.x; s0.y += a0.y; s0.z += a0.z; s0.w += a0.w;
            s1.x += a1.x; s1.y += a1.y; s1.z += a1.z; s1.w += a1.w;
            s2.x += a2.x; s2.y += a2.y; s2.z += a2.z; s2.w += a2.w;
            s3.x += a3.x; s3.y += a3.y; s3.z += a3.z; s3.w += a3.w;
        }
        float4 r;
        r.x = (s0.x + s1.x) + (s2.x + s3.x);
        r.y = (s0.y + s1.y) + (s2.y + s3.y);
        r.z = (s0.z + s1.z) + (s2.z + s3.z);
        r.w = (s0.w + s1.w) + (s2.w + s3.w);
        csum[q] = r;
        tsum += (r.x + r.y) + (r.z + r.w);
    }
    for (int off = 32; off; off >>= 1) tsum += __shfl_down(tsum, off);
    if (lane == 0) red[w][0] = tsum;
    __syncthreads();
    if (tid == 0) {
        const float tot   = (red[0][0] + red[1][0]) + (red[2][0] + red[3][0]);
        const float scale = bc[1];
        const float denom = fmaxf(tot * scale, 1e-5f);
        bc[2] = scale / denom;
    }
    __syncthreads();
    const float factor = bc[2];
    float4* ob = reinterpret_cast<float4*>(out + b * NCELL);
#pragma unroll
    for (int q = 0; q < 4; ++q) {
        float4 r = csum[q];
        r.x *= factor; r.y *= factor; r.z *= factor; r.w *= factor;
        ob[q * 256 + tid] = r;
    }
}

// ---------------------------------------------------------------------------
extern "C" void kernel_launch(void* const* d_in, const int* in_sizes, int n_in,
                              void* d_out, int out_size, void* d_ws, size_t ws_size,
                              hipStream_t stream) {
    const float* T = (const float*)d_in[0];   // [B, NV, 2] f32
    // d_in[1] (S) is a deterministic 64x64 meshgrid in [0,1]^2 — derived inline.

    unsigned int* cnt      = (unsigned int*)d_ws;               // 8 counters
    float*        partials = (float*)d_ws + PARTIALS_OFF;       // 4 MB

    hipMemsetAsync(cnt, 0, BATCH * sizeof(unsigned int), stream);
    kde_elect<<<BATCH * SPLITS, 256, 0, stream>>>(T, cnt, partials, (float*)d_out);
}